// Round 1
// baseline (275.786 us; speedup 1.0000x reference)
//
#include <hip/hip_runtime.h>
#include <hip/hip_bf16.h>

#define DD 128
#define NPTS 8192
#define BBATCH 32
#define BK 64
#define LAM 0.01f

typedef __attribute__((ext_vector_type(8))) short bf16x8;
typedef __attribute__((ext_vector_type(16))) float f32x16;

// round-to-nearest-even f32 -> bf16 (as unsigned 16-bit pattern)
__device__ __forceinline__ unsigned f2bf_u(float f) {
    unsigned u = __builtin_bit_cast(unsigned, f);
    return (u + 0x7FFFu + ((u >> 16) & 1u)) >> 16;
}

// per-row chunk swizzle: breaks both read-phase and transpose-write-phase bank collisions
__device__ __forceinline__ int swz(int d) { return ((d >> 2) ^ d) & 7; }

// Kernel 1: per (batch, k-chunk): partial Gram S = X^T X via bf16 MFMA (fp32 accum),
// plus fp32 colsum and fp32 key-dots (column-0 products) for exact sort keys.
__global__ __launch_bounds__(256) void gram_stats(
    const float* __restrict__ x, float* __restrict__ Spart,
    float* __restrict__ CSpart, float* __restrict__ KDpart, int P)
{
    // XT[d][k] bf16, element (d,k) stored at d*BK + ((k>>3) ^ swz(d))*8 + (k&7)
    __shared__ short XT[DD * BK];

    const int blk = blockIdx.x;
    const int b   = blk & 31;
    const int kc  = blk >> 5;
    const int rowsPerBlk = NPTS / P;
    const int k0g = kc * rowsPerBlk;
    const float* xb = x + (size_t)b * NPTS * DD;

    const int tid  = threadIdx.x;
    const int lane = tid & 63;
    const int wave = tid >> 6;
    const int dg   = tid & 31;   // owns d = 4*dg + i, i=0..3
    const int aa   = tid >> 5;   // 0..7, owns rows 4*aa + r, r=0..3 (per pass)

    const int wr = (wave >> 1) * 64;   // wave-tile row base
    const int wc = (wave & 1) * 64;    // wave-tile col base

    f32x16 acc00 = {}; f32x16 acc01 = {}; f32x16 acc10 = {}; f32x16 acc11 = {};
    float csum[4] = {0.f, 0.f, 0.f, 0.f};
    float kdot[4] = {0.f, 0.f, 0.f, 0.f};

    for (int kt = 0; kt < rowsPerBlk; kt += BK) {
        __syncthreads();   // protect previous compute reads before restaging
        #pragma unroll
        for (int pass = 0; pass < 2; ++pass) {
            const int krow = kt + pass * 32 + aa * 4;
            const float4* src = (const float4*)(xb + (size_t)(k0g + krow) * DD) + dg;
            float4 m0 = src[0];
            float4 m1 = src[DD / 4];
            float4 m2 = src[2 * (DD / 4)];
            float4 m3 = src[3 * (DD / 4)];
            // broadcast x[k][0] from the lane holding d=0..3 of this half-wave's rows
            float x00 = __shfl(m0.x, lane & 32);
            float x01 = __shfl(m1.x, lane & 32);
            float x02 = __shfl(m2.x, lane & 32);
            float x03 = __shfl(m3.x, lane & 32);
            float e0[4] = {m0.x, m0.y, m0.z, m0.w};
            float e1[4] = {m1.x, m1.y, m1.z, m1.w};
            float e2[4] = {m2.x, m2.y, m2.z, m2.w};
            float e3[4] = {m3.x, m3.y, m3.z, m3.w};
            const int chunk = pass * 4 + (aa >> 1);
            #pragma unroll
            for (int i = 0; i < 4; ++i) {
                csum[i] += e0[i] + e1[i] + e2[i] + e3[i];
                kdot[i] += x00 * e0[i] + x01 * e1[i] + x02 * e2[i] + x03 * e3[i];
                const int d = 4 * dg + i;
                unsigned u0 = f2bf_u(e0[i]) | (f2bf_u(e1[i]) << 16);
                unsigned u1 = f2bf_u(e2[i]) | (f2bf_u(e3[i]) << 16);
                const int addr = d * BK + ((chunk ^ swz(d)) * 8) + (aa & 1) * 4;
                uint2 v; v.x = u0; v.y = u1;
                *(uint2*)(XT + addr) = v;   // ds_write_b64, 4 consecutive k at fixed d
            }
        }
        __syncthreads();
        #pragma unroll
        for (int ks = 0; ks < BK / 16; ++ks) {
            const int chunkBase = ks * 2 + (lane >> 5);
            const int m = lane & 31;
            const int a0d = wr + m, a1d = wr + 32 + m;
            const int b0d = wc + m, b1d = wc + 32 + m;
            bf16x8 a0 = *(const bf16x8*)(XT + a0d * BK + ((chunkBase ^ swz(a0d)) * 8));
            bf16x8 a1 = *(const bf16x8*)(XT + a1d * BK + ((chunkBase ^ swz(a1d)) * 8));
            bf16x8 b0 = *(const bf16x8*)(XT + b0d * BK + ((chunkBase ^ swz(b0d)) * 8));
            bf16x8 b1 = *(const bf16x8*)(XT + b1d * BK + ((chunkBase ^ swz(b1d)) * 8));
            acc00 = __builtin_amdgcn_mfma_f32_32x32x16_bf16(a0, b0, acc00, 0, 0, 0);
            acc01 = __builtin_amdgcn_mfma_f32_32x32x16_bf16(a0, b1, acc01, 0, 0, 0);
            acc10 = __builtin_amdgcn_mfma_f32_32x32x16_bf16(a1, b0, acc10, 0, 0, 0);
            acc11 = __builtin_amdgcn_mfma_f32_32x32x16_bf16(a1, b1, acc11, 0, 0, 0);
        }
    }

    // write partial Gram (C/D layout: col=lane&31, row=(r&3)+8*(r>>2)+4*(lane>>5))
    float* Sp = Spart + ((size_t)b * P + kc) * (DD * DD);
    const int colLane = lane & 31;
    const int rowHw = 4 * (lane >> 5);
    {
        const f32x16* accs[4] = {&acc00, &acc01, &acc10, &acc11};
        const int rb[4] = {wr, wr, wr + 32, wr + 32};
        const int cb[4] = {wc, wc + 32, wc, wc + 32};
        #pragma unroll
        for (int t = 0; t < 4; ++t) {
            #pragma unroll
            for (int r = 0; r < 16; ++r) {
                int row = rb[t] + (r & 3) + 8 * (r >> 2) + rowHw;
                Sp[row * DD + cb[t] + colLane] = (*accs[t])[r];
            }
        }
    }

    // block-reduce colsum / keydot (8 threads share each d-group)
    __syncthreads();
    float* red = (float*)XT;
    #pragma unroll
    for (int i = 0; i < 4; ++i) {
        red[tid] = csum[i];
        __syncthreads();
        if (tid < 32) {
            float s = 0.f;
            #pragma unroll
            for (int g = 0; g < 8; ++g) s += red[g * 32 + tid];
            CSpart[((size_t)b * P + kc) * DD + 4 * tid + i] = s;
        }
        __syncthreads();
        red[tid] = kdot[i];
        __syncthreads();
        if (tid < 32) {
            float s = 0.f;
            #pragma unroll
            for (int g = 0; g < 8; ++g) s += red[g * 32 + tid];
            KDpart[((size_t)b * P + kc) * DD + 4 * tid + i] = s;
        }
        __syncthreads();
    }
}

// Kernel 2: reduce partials, fixup to covariance, rank rows lexicographically
// by fp32 keys (column 0), scatter sorted rows to output.
__global__ __launch_bounds__(256) void reduce_sort(
    const float* __restrict__ Spart, const float* __restrict__ CSpart,
    const float* __restrict__ KDpart, float* __restrict__ out, int P)
{
    __shared__ float S[DD * 132];   // padded rows (+4) to spread banks
    __shared__ float cs[DD];
    __shared__ float kdv[DD];
    __shared__ float key[DD];
    __shared__ int rankArr[DD];

    const int b = blockIdx.x;
    const int tid = threadIdx.x;
    const float* Sp = Spart + (size_t)b * P * (DD * DD);

    for (int e = tid * 4; e < DD * DD; e += 256 * 4) {
        float4 acc = {0.f, 0.f, 0.f, 0.f};
        for (int p = 0; p < P; ++p) {
            float4 v = *(const float4*)(Sp + (size_t)p * DD * DD + e);
            acc.x += v.x; acc.y += v.y; acc.z += v.z; acc.w += v.w;
        }
        *(float4*)(&S[(e >> 7) * 132 + (e & 127)]) = acc;
    }
    if (tid < DD) {
        float s = 0.f, k = 0.f;
        for (int p = 0; p < P; ++p) {
            s += CSpart[((size_t)b * P + p) * DD + tid];
            k += KDpart[((size_t)b * P + p) * DD + tid];
        }
        cs[tid] = s;
        kdv[tid] = k;
    }
    __syncthreads();
    if (tid < DD) {
        key[tid] = (kdv[tid] - cs[tid] * cs[0] * (1.f / NPTS)) * (1.f / (NPTS - 1))
                 + ((tid == 0) ? LAM : 0.f);
    }
    __syncthreads();

    auto covval = [&](int i, int j) -> float {
        return (S[i * 132 + j] - cs[i] * cs[j] * (1.f / NPTS)) * (1.f / (NPTS - 1))
             + ((i == j) ? LAM : 0.f);
    };

    if (tid < DD) {
        const float ki = key[tid];
        int r = 0;
        for (int j = 0; j < DD; ++j) {
            if (j == tid) continue;
            const float kj = key[j];
            bool less;
            if (kj != ki) {
                less = (kj < ki);
            } else {
                less = (j < tid);   // full-tie fallback (stable)
                for (int t = 1; t < DD; ++t) {
                    float a = covval(j, t), c = covval(tid, t);
                    if (a != c) { less = (a < c); break; }
                }
            }
            r += less ? 1 : 0;
        }
        rankArr[tid] = r;
    }
    __syncthreads();

    const int i = tid >> 1;
    const int jh = (tid & 1) * 64;
    float* ob = out + (size_t)b * DD * DD + (size_t)rankArr[i] * DD;
    for (int j = jh; j < jh + 64; j += 4) {
        float4 v;
        v.x = (j == 0) ? key[i] : covval(i, j);
        v.y = covval(i, j + 1);
        v.z = covval(i, j + 2);
        v.w = covval(i, j + 3);
        *(float4*)(ob + j) = v;
    }
}

extern "C" void kernel_launch(void* const* d_in, const int* in_sizes, int n_in,
                              void* d_out, int out_size, void* d_ws, size_t ws_size,
                              hipStream_t stream)
{
    const float* x = (const float*)d_in[0];
    float* out = (float*)d_out;

    // pick largest k-split whose deterministic partials fit the workspace
    int P = 16;
    while (P > 1) {
        size_t need = (size_t)BBATCH * P * (DD * DD + 2 * DD) * sizeof(float);
        if (need <= ws_size) break;
        P >>= 1;
    }
    size_t nS = (size_t)BBATCH * P * DD * DD;
    size_t nC = (size_t)BBATCH * P * DD;
    float* Spart  = (float*)d_ws;
    float* CSpart = Spart + nS;
    float* KDpart = CSpart + nC;

    gram_stats<<<dim3(32 * P), dim3(256), 0, stream>>>(x, Spart, CSpart, KDpart, P);
    reduce_sort<<<dim3(BBATCH), dim3(256), 0, stream>>>(Spart, CSpart, KDpart, out, P);
}

// Round 2
// 216.407 us; speedup vs baseline: 1.2744x; 1.2744x over previous
//
#include <hip/hip_runtime.h>
#include <hip/hip_bf16.h>

#define DD 128
#define NPTS 8192
#define BBATCH 32
#define BK 64
#define LAM 0.01f

typedef __attribute__((ext_vector_type(8))) short bf16x8;
typedef __attribute__((ext_vector_type(16))) float f32x16;

// round-to-nearest-even f32 -> bf16 (as unsigned 16-bit pattern)
__device__ __forceinline__ unsigned f2bf_u(float f) {
    unsigned u = __builtin_bit_cast(unsigned, f);
    return (u + 0x7FFFu + ((u >> 16) & 1u)) >> 16;
}
__device__ __forceinline__ float bf2f(unsigned short u) {
    unsigned v = ((unsigned)u) << 16;
    return __builtin_bit_cast(float, v);
}

// per-row chunk swizzle: breaks both read-phase and transpose-write-phase bank collisions
__device__ __forceinline__ int swz(int d) { return ((d >> 2) ^ d) & 7; }

// Kernel 1: per (batch, k-chunk): partial Gram S = X^T X via bf16 MFMA (fp32 accum),
// stored to ws as bf16 (RNE). fp32 colsum and fp32 key-dots kept exact for the sort.
__global__ __launch_bounds__(256) void gram_stats(
    const float* __restrict__ x, unsigned short* __restrict__ Spart,
    float* __restrict__ CSpart, float* __restrict__ KDpart, int P)
{
    // XT[d][k] bf16, element (d,k) stored at d*BK + ((k>>3) ^ swz(d))*8 + (k&7)
    __shared__ short XT[DD * BK];

    const int blk = blockIdx.x;
    const int b   = blk & 31;
    const int kc  = blk >> 5;
    const int rowsPerBlk = NPTS / P;
    const int k0g = kc * rowsPerBlk;
    const float* xb = x + (size_t)b * NPTS * DD;

    const int tid  = threadIdx.x;
    const int lane = tid & 63;
    const int wave = tid >> 6;
    const int dg   = tid & 31;   // owns d = 4*dg + i, i=0..3
    const int aa   = tid >> 5;   // 0..7, owns rows 4*aa + r per pass

    const int wr = (wave >> 1) * 64;   // wave-tile row base
    const int wc = (wave & 1) * 64;    // wave-tile col base

    f32x16 acc00 = {}; f32x16 acc01 = {}; f32x16 acc10 = {}; f32x16 acc11 = {};
    float csum[4] = {0.f, 0.f, 0.f, 0.f};
    float kdot[4] = {0.f, 0.f, 0.f, 0.f};

    for (int kt = 0; kt < rowsPerBlk; kt += BK) {
        __syncthreads();
        #pragma unroll
        for (int pass = 0; pass < 2; ++pass) {
            const int krow = kt + pass * 32 + aa * 4;
            const float4* src = (const float4*)(xb + (size_t)(k0g + krow) * DD) + dg;
            float4 m0 = src[0];
            float4 m1 = src[DD / 4];
            float4 m2 = src[2 * (DD / 4)];
            float4 m3 = src[3 * (DD / 4)];
            float x00 = __shfl(m0.x, lane & 32);
            float x01 = __shfl(m1.x, lane & 32);
            float x02 = __shfl(m2.x, lane & 32);
            float x03 = __shfl(m3.x, lane & 32);
            float e0[4] = {m0.x, m0.y, m0.z, m0.w};
            float e1[4] = {m1.x, m1.y, m1.z, m1.w};
            float e2[4] = {m2.x, m2.y, m2.z, m2.w};
            float e3[4] = {m3.x, m3.y, m3.z, m3.w};
            const int chunk = pass * 4 + (aa >> 1);
            #pragma unroll
            for (int i = 0; i < 4; ++i) {
                csum[i] += e0[i] + e1[i] + e2[i] + e3[i];
                kdot[i] += x00 * e0[i] + x01 * e1[i] + x02 * e2[i] + x03 * e3[i];
                const int d = 4 * dg + i;
                unsigned u0 = f2bf_u(e0[i]) | (f2bf_u(e1[i]) << 16);
                unsigned u1 = f2bf_u(e2[i]) | (f2bf_u(e3[i]) << 16);
                const int addr = d * BK + ((chunk ^ swz(d)) * 8) + (aa & 1) * 4;
                uint2 v; v.x = u0; v.y = u1;
                *(uint2*)(XT + addr) = v;
            }
        }
        __syncthreads();
        #pragma unroll
        for (int ks = 0; ks < BK / 16; ++ks) {
            const int chunkBase = ks * 2 + (lane >> 5);
            const int m = lane & 31;
            const int a0d = wr + m, a1d = wr + 32 + m;
            const int b0d = wc + m, b1d = wc + 32 + m;
            bf16x8 a0 = *(const bf16x8*)(XT + a0d * BK + ((chunkBase ^ swz(a0d)) * 8));
            bf16x8 a1 = *(const bf16x8*)(XT + a1d * BK + ((chunkBase ^ swz(a1d)) * 8));
            bf16x8 b0 = *(const bf16x8*)(XT + b0d * BK + ((chunkBase ^ swz(b0d)) * 8));
            bf16x8 b1 = *(const bf16x8*)(XT + b1d * BK + ((chunkBase ^ swz(b1d)) * 8));
            acc00 = __builtin_amdgcn_mfma_f32_32x32x16_bf16(a0, b0, acc00, 0, 0, 0);
            acc01 = __builtin_amdgcn_mfma_f32_32x32x16_bf16(a0, b1, acc01, 0, 0, 0);
            acc10 = __builtin_amdgcn_mfma_f32_32x32x16_bf16(a1, b0, acc10, 0, 0, 0);
            acc11 = __builtin_amdgcn_mfma_f32_32x32x16_bf16(a1, b1, acc11, 0, 0, 0);
        }
    }

    // write partial Gram as bf16 (C/D layout: col=lane&31, row=(r&3)+8*(r>>2)+4*(lane>>5))
    unsigned short* Sp = Spart + ((size_t)b * P + kc) * (DD * DD);
    const int colLane = lane & 31;
    const int rowHw = 4 * (lane >> 5);
    {
        const f32x16* accs[4] = {&acc00, &acc01, &acc10, &acc11};
        const int rb[4] = {wr, wr, wr + 32, wr + 32};
        const int cb[4] = {wc, wc + 32, wc, wc + 32};
        #pragma unroll
        for (int t = 0; t < 4; ++t) {
            #pragma unroll
            for (int r = 0; r < 16; ++r) {
                int row = rb[t] + (r & 3) + 8 * (r >> 2) + rowHw;
                Sp[row * DD + cb[t] + colLane] = (unsigned short)f2bf_u((*accs[t])[r]);
            }
        }
    }

    // block-reduce colsum / keydot
    __syncthreads();
    float* red = (float*)XT;
    #pragma unroll
    for (int i = 0; i < 4; ++i) {
        red[tid] = csum[i];
        __syncthreads();
        if (tid < 32) {
            float s = 0.f;
            #pragma unroll
            for (int g = 0; g < 8; ++g) s += red[g * 32 + tid];
            CSpart[((size_t)b * P + kc) * DD + 4 * tid + i] = s;
        }
        __syncthreads();
        red[tid] = kdot[i];
        __syncthreads();
        if (tid < 32) {
            float s = 0.f;
            #pragma unroll
            for (int g = 0; g < 8; ++g) s += red[g * 32 + tid];
            KDpart[((size_t)b * P + kc) * DD + 4 * tid + i] = s;
        }
        __syncthreads();
    }
}

// Kernel 2: block (b, seg) — redundantly reduce colsums + fp32 keys, compute ranks,
// reduce its 16-row segment of the bf16 partial Grams, fixup, scatter rows to d_out.
__global__ __launch_bounds__(256) void reduce_sort2(
    const unsigned short* __restrict__ Spart, const float* __restrict__ CSpart,
    const float* __restrict__ KDpart, float* __restrict__ out, int P)
{
    __shared__ float cs[DD];
    __shared__ float key[DD];
    __shared__ int rankArr[DD];

    const int b   = blockIdx.x;
    const int seg = blockIdx.y;
    const int tid = threadIdx.x;
    const float invN = 1.f / NPTS;
    const float invNm1 = 1.f / (NPTS - 1);

    float kd = 0.f;
    if (tid < DD) {
        float s = 0.f;
        for (int p = 0; p < P; ++p) {
            s  += CSpart[((size_t)b * P + p) * DD + tid];
            kd += KDpart[((size_t)b * P + p) * DD + tid];
        }
        cs[tid] = s;
    }
    __syncthreads();
    if (tid < DD) {
        key[tid] = (kd - cs[tid] * cs[0] * invN) * invNm1 + ((tid == 0) ? LAM : 0.f);
    }
    __syncthreads();

    // segment reduce: 2048 elements, 8 per thread
    const int base = seg * (16 * DD) + tid * 8;
    float acc[8] = {0.f, 0.f, 0.f, 0.f, 0.f, 0.f, 0.f, 0.f};
    for (int p = 0; p < P; ++p) {
        bf16x8 v = *(const bf16x8*)(Spart + ((size_t)b * P + p) * (DD * DD) + base);
        #pragma unroll
        for (int i = 0; i < 8; ++i) acc[i] += bf2f((unsigned short)v[i]);
    }

    // ranks (tie-break walks the bf16-reduced cov — dead path for generic floats)
    auto covv = [&](int i, int j) -> float {
        float s = 0.f;
        for (int p = 0; p < P; ++p)
            s += bf2f(Spart[((size_t)b * P + p) * (DD * DD) + i * DD + j]);
        return (s - cs[i] * cs[j] * invN) * invNm1 + ((i == j) ? LAM : 0.f);
    };
    if (tid < DD) {
        const float ki = key[tid];
        int r = 0;
        for (int j = 0; j < DD; ++j) {
            if (j == tid) continue;
            const float kj = key[j];
            bool less;
            if (kj != ki) {
                less = (kj < ki);
            } else {
                less = (j < tid);
                for (int t = 1; t < DD; ++t) {
                    float a = covv(j, t), c = covv(tid, t);
                    if (a != c) { less = (a < c); break; }
                }
            }
            r += less ? 1 : 0;
        }
        rankArr[tid] = r;
    }
    __syncthreads();

    // fixup + scatter: this thread's 8 elements live in one row
    const int row = seg * 16 + (tid >> 4);
    const int j0  = (tid & 15) * 8;
    const float ci = cs[row];
    float4 v0, v1;
    float* o = out + (size_t)b * DD * DD + (size_t)rankArr[row] * DD + j0;
    {
        float vals[8];
        #pragma unroll
        for (int i = 0; i < 8; ++i) {
            const int j = j0 + i;
            vals[i] = (acc[i] - ci * cs[j] * invN) * invNm1 + ((row == j) ? LAM : 0.f);
        }
        v0.x = vals[0]; v0.y = vals[1]; v0.z = vals[2]; v0.w = vals[3];
        v1.x = vals[4]; v1.y = vals[5]; v1.z = vals[6]; v1.w = vals[7];
    }
    *(float4*)(o)     = v0;
    *(float4*)(o + 4) = v1;
}

extern "C" void kernel_launch(void* const* d_in, const int* in_sizes, int n_in,
                              void* d_out, int out_size, void* d_ws, size_t ws_size,
                              hipStream_t stream)
{
    const float* x = (const float*)d_in[0];
    float* out = (float*)d_out;

    // bf16 partial Grams: pick largest k-split P that fits the workspace
    int P = 16;
    while (P > 1) {
        size_t need = (size_t)BBATCH * P * (DD * DD) * sizeof(unsigned short)
                    + (size_t)BBATCH * P * 2 * DD * sizeof(float);
        if (need <= ws_size) break;
        P >>= 1;
    }
    size_t nS = (size_t)BBATCH * P * DD * DD;          // shorts
    unsigned short* Spart = (unsigned short*)d_ws;
    float* CSpart = (float*)(Spart + nS);
    float* KDpart = CSpart + (size_t)BBATCH * P * DD;

    gram_stats<<<dim3(32 * P), dim3(256), 0, stream>>>(x, Spart, CSpart, KDpart, P);
    reduce_sort2<<<dim3(BBATCH, 8), dim3(256), 0, stream>>>(Spart, CSpart, KDpart, out, P);
}

// Round 3
// 207.763 us; speedup vs baseline: 1.3274x; 1.0416x over previous
//
#include <hip/hip_runtime.h>
#include <hip/hip_bf16.h>

#define DD 128
#define NPTS 8192
#define BBATCH 32
#define BK 64
#define LAM 0.01f

typedef __attribute__((ext_vector_type(8))) short bf16x8;
typedef __attribute__((ext_vector_type(16))) float f32x16;

__device__ __forceinline__ unsigned f2bf_u(float f) {
    unsigned u = __builtin_bit_cast(unsigned, f);
    return (u + 0x7FFFu + ((u >> 16) & 1u)) >> 16;
}
__device__ __forceinline__ float bf2f(unsigned short u) {
    unsigned v = ((unsigned)u) << 16;
    return __builtin_bit_cast(float, v);
}
__device__ __forceinline__ int swz(int d) { return ((d >> 2) ^ d) & 7; }

// Kernel 1: per (batch, k-chunk) partial Gram via bf16 MFMA, software-pipelined
// staging (next tile's global loads in flight across the MFMA section).
// fp32 colsum + key-dots (col-0 products) kept exact for the sort.
template<int P>
__global__ __launch_bounds__(256) void gram_stats(
    const float* __restrict__ x, unsigned short* __restrict__ Spart,
    float* __restrict__ CSpart, float* __restrict__ KDpart)
{
    __shared__ short XT[DD * BK];   // XT[d][k]: d*BK + ((k>>3)^swz(d))*8 + (k&7)
    constexpr int rowsPerBlk = NPTS / P;
    constexpr int T = rowsPerBlk / BK;

    const int blk = blockIdx.x;
    const int b   = blk & 31;
    const int kc  = blk >> 5;
    const int k0g = kc * rowsPerBlk;
    const float* xb = x + (size_t)b * NPTS * DD;

    const int tid  = threadIdx.x;
    const int lane = tid & 63;
    const int wave = tid >> 6;
    const int dg   = tid & 31;
    const int aa   = tid >> 5;
    const int wr = (wave >> 1) * 64;
    const int wc = (wave & 1) * 64;

    f32x16 acc00 = {}; f32x16 acc01 = {}; f32x16 acc10 = {}; f32x16 acc11 = {};
    float csum[4] = {0.f, 0.f, 0.f, 0.f};
    float kdot[4] = {0.f, 0.f, 0.f, 0.f};

    float4 Ra[4], Rb[4];
    auto loadPass = [&](float4* Rg, int krow0) {
        const float4* s = (const float4*)(xb + (size_t)(k0g + krow0 + aa * 4) * DD) + dg;
        Rg[0] = s[0]; Rg[1] = s[32]; Rg[2] = s[64]; Rg[3] = s[96];
    };
    auto consumePass = [&](const float4* Rg, int pass) {
        float4 m0 = Rg[0], m1 = Rg[1], m2 = Rg[2], m3 = Rg[3];
        float x00 = __shfl(m0.x, lane & 32), x01 = __shfl(m1.x, lane & 32);
        float x02 = __shfl(m2.x, lane & 32), x03 = __shfl(m3.x, lane & 32);
        float e0[4] = {m0.x, m0.y, m0.z, m0.w};
        float e1[4] = {m1.x, m1.y, m1.z, m1.w};
        float e2[4] = {m2.x, m2.y, m2.z, m2.w};
        float e3[4] = {m3.x, m3.y, m3.z, m3.w};
        const int chunk = pass * 4 + (aa >> 1);
        #pragma unroll
        for (int i = 0; i < 4; ++i) {
            csum[i] += e0[i] + e1[i] + e2[i] + e3[i];
            kdot[i] += x00 * e0[i] + x01 * e1[i] + x02 * e2[i] + x03 * e3[i];
            const int d = 4 * dg + i;
            unsigned u0 = f2bf_u(e0[i]) | (f2bf_u(e1[i]) << 16);
            unsigned u1 = f2bf_u(e2[i]) | (f2bf_u(e3[i]) << 16);
            const int addr = d * BK + ((chunk ^ swz(d)) * 8) + (aa & 1) * 4;
            uint2 v; v.x = u0; v.y = u1;
            *(uint2*)(XT + addr) = v;
        }
    };

    loadPass(Ra, 0);
    loadPass(Rb, 32);

    #pragma unroll
    for (int t = 0; t < T; ++t) {
        __syncthreads();                 // previous MFMA done reading LDS
        consumePass(Ra, 0);              // waits only on Ra's loads
        consumePass(Rb, 1);
        if (t + 1 < T) {                 // prefetch next tile before MFMA section
            loadPass(Ra, (t + 1) * BK);
            loadPass(Rb, (t + 1) * BK + 32);
        }
        __syncthreads();
        #pragma unroll
        for (int ks = 0; ks < BK / 16; ++ks) {
            const int chunkBase = ks * 2 + (lane >> 5);
            const int m = lane & 31;
            const int a0d = wr + m, a1d = wr + 32 + m;
            const int b0d = wc + m, b1d = wc + 32 + m;
            bf16x8 a0 = *(const bf16x8*)(XT + a0d * BK + ((chunkBase ^ swz(a0d)) * 8));
            bf16x8 a1 = *(const bf16x8*)(XT + a1d * BK + ((chunkBase ^ swz(a1d)) * 8));
            bf16x8 b0 = *(const bf16x8*)(XT + b0d * BK + ((chunkBase ^ swz(b0d)) * 8));
            bf16x8 b1 = *(const bf16x8*)(XT + b1d * BK + ((chunkBase ^ swz(b1d)) * 8));
            acc00 = __builtin_amdgcn_mfma_f32_32x32x16_bf16(a0, b0, acc00, 0, 0, 0);
            acc01 = __builtin_amdgcn_mfma_f32_32x32x16_bf16(a0, b1, acc01, 0, 0, 0);
            acc10 = __builtin_amdgcn_mfma_f32_32x32x16_bf16(a1, b0, acc10, 0, 0, 0);
            acc11 = __builtin_amdgcn_mfma_f32_32x32x16_bf16(a1, b1, acc11, 0, 0, 0);
        }
    }

    // write partial Gram as bf16 (C/D layout: col=lane&31, row=(r&3)+8*(r>>2)+4*(lane>>5))
    unsigned short* Sp = Spart + ((size_t)b * P + kc) * (DD * DD);
    const int colLane = lane & 31;
    const int rowHw = 4 * (lane >> 5);
    {
        const f32x16* accs[4] = {&acc00, &acc01, &acc10, &acc11};
        const int rb[4] = {wr, wr, wr + 32, wr + 32};
        const int cb[4] = {wc, wc + 32, wc, wc + 32};
        #pragma unroll
        for (int t = 0; t < 4; ++t) {
            #pragma unroll
            for (int r = 0; r < 16; ++r) {
                int row = rb[t] + (r & 3) + 8 * (r >> 2) + rowHw;
                Sp[row * DD + cb[t] + colLane] = (unsigned short)f2bf_u((*accs[t])[r]);
            }
        }
    }

    // block-reduce colsum / keydot
    __syncthreads();
    float* red = (float*)XT;
    #pragma unroll
    for (int i = 0; i < 4; ++i) {
        red[tid] = csum[i];
        __syncthreads();
        if (tid < 32) {
            float s = 0.f;
            #pragma unroll
            for (int g = 0; g < 8; ++g) s += red[g * 32 + tid];
            CSpart[((size_t)b * P + kc) * DD + 4 * tid + i] = s;
        }
        __syncthreads();
        red[tid] = kdot[i];
        __syncthreads();
        if (tid < 32) {
            float s = 0.f;
            #pragma unroll
            for (int g = 0; g < 8; ++g) s += red[g * 32 + tid];
            KDpart[((size_t)b * P + kc) * DD + 4 * tid + i] = s;
        }
        __syncthreads();
    }
}

// Kernel 2: one block per batch — reduce fp32 colsums/key-dots, compute keys,
// rank rows by fp32 key (index tie-break; exact fp32 ties don't occur for
// generic float data), store cs + ranks for the scatter kernel.
template<int P>
__global__ __launch_bounds__(128) void keys_ranks(
    const float* __restrict__ CSpart, const float* __restrict__ KDpart,
    float* __restrict__ csOut, int* __restrict__ rankOut)
{
    __shared__ float csh[DD];
    __shared__ float key[DD];
    const int b = blockIdx.x;
    const int tid = threadIdx.x;   // 128
    float s = 0.f, kd = 0.f;
    #pragma unroll
    for (int p = 0; p < P; ++p) {
        s  += CSpart[((size_t)b * P + p) * DD + tid];
        kd += KDpart[((size_t)b * P + p) * DD + tid];
    }
    csh[tid] = s;
    __syncthreads();
    const float k = (kd - s * csh[0] * (1.f / NPTS)) * (1.f / (NPTS - 1))
                  + ((tid == 0) ? LAM : 0.f);
    key[tid] = k;
    __syncthreads();
    int r = 0;
    #pragma unroll 8
    for (int j = 0; j < DD; ++j) {
        const float kj = key[j];
        r += (kj < k) || (kj == k && j < tid);
    }
    csOut[b * DD + tid] = s;
    rankOut[b * DD + tid] = r;
}

// Kernel 3: block (b, seg of 8 rows) — reduce bf16 partial Grams, fixup
// mean/ridge, scatter rows to ranked position in d_out.
template<int P>
__global__ __launch_bounds__(256) void reduce_scatter(
    const unsigned short* __restrict__ Spart, const float* __restrict__ csOut,
    const int* __restrict__ rankOut, float* __restrict__ out)
{
    __shared__ float csh[DD];
    __shared__ int rk[8];
    const int b = blockIdx.x;
    const int seg = blockIdx.y;
    const int tid = threadIdx.x;
    if (tid < DD) csh[tid] = csOut[b * DD + tid];
    if (tid < 8)  rk[tid] = rankOut[b * DD + seg * 8 + tid];

    const int base = seg * (8 * DD) + tid * 4;
    float a0 = 0.f, a1 = 0.f, a2 = 0.f, a3 = 0.f;
    #pragma unroll
    for (int p = 0; p < P; ++p) {
        uint2 v = *(const uint2*)(Spart + ((size_t)b * P + p) * (DD * DD) + base);
        a0 += bf2f((unsigned short)(v.x & 0xFFFFu));
        a1 += bf2f((unsigned short)(v.x >> 16));
        a2 += bf2f((unsigned short)(v.y & 0xFFFFu));
        a3 += bf2f((unsigned short)(v.y >> 16));
    }
    __syncthreads();
    const int row = seg * 8 + (tid >> 5);
    const int j0  = (tid & 31) * 4;
    const float ci = csh[row];
    const float invN = 1.f / NPTS, invNm1 = 1.f / (NPTS - 1);
    float4 v;
    v.x = (a0 - ci * csh[j0 + 0] * invN) * invNm1 + ((row == j0 + 0) ? LAM : 0.f);
    v.y = (a1 - ci * csh[j0 + 1] * invN) * invNm1 + ((row == j0 + 1) ? LAM : 0.f);
    v.z = (a2 - ci * csh[j0 + 2] * invN) * invNm1 + ((row == j0 + 2) ? LAM : 0.f);
    v.w = (a3 - ci * csh[j0 + 3] * invN) * invNm1 + ((row == j0 + 3) ? LAM : 0.f);
    float* o = out + (size_t)b * DD * DD + (size_t)rk[tid >> 5] * DD + j0;
    *(float4*)o = v;
}

template<int P>
static void launch_all(const float* x, float* out, void* d_ws, hipStream_t stream)
{
    size_t nS = (size_t)BBATCH * P * DD * DD;           // shorts
    unsigned short* Spart = (unsigned short*)d_ws;
    float* CSpart = (float*)(Spart + nS);
    float* KDpart = CSpart + (size_t)BBATCH * P * DD;
    float* csOut  = KDpart + (size_t)BBATCH * P * DD;
    int*   rankOut = (int*)(csOut + (size_t)BBATCH * DD);

    gram_stats<P><<<dim3(32 * P), dim3(256), 0, stream>>>(x, Spart, CSpart, KDpart);
    keys_ranks<P><<<dim3(BBATCH), dim3(128), 0, stream>>>(CSpart, KDpart, csOut, rankOut);
    reduce_scatter<P><<<dim3(BBATCH, 16), dim3(256), 0, stream>>>(Spart, csOut, rankOut, out);
}

extern "C" void kernel_launch(void* const* d_in, const int* in_sizes, int n_in,
                              void* d_out, int out_size, void* d_ws, size_t ws_size,
                              hipStream_t stream)
{
    const float* x = (const float*)d_in[0];
    float* out = (float*)d_out;

    auto need = [](int P) {
        return (size_t)BBATCH * P * DD * DD * sizeof(unsigned short)
             + (size_t)BBATCH * P * 2 * DD * sizeof(float)
             + (size_t)BBATCH * DD * (sizeof(float) + sizeof(int));
    };
    if (need(32) <= ws_size)      launch_all<32>(x, out, d_ws, stream);
    else if (need(16) <= ws_size) launch_all<16>(x, out, d_ws, stream);
    else                          launch_all<8>(x, out, d_ws, stream);
}

// Round 4
// 198.426 us; speedup vs baseline: 1.3899x; 1.0471x over previous
//
#include <hip/hip_runtime.h>
#include <hip/hip_bf16.h>

#define DD 128
#define NPTS 8192
#define BBATCH 32
#define BK 64
#define LAM 0.01f

typedef __attribute__((ext_vector_type(8))) short bf16x8;
typedef __attribute__((ext_vector_type(16))) float f32x16;

__device__ __forceinline__ unsigned f2bf_u(float f) {
    unsigned u = __builtin_bit_cast(unsigned, f);
    return (u + 0x7FFFu + ((u >> 16) & 1u)) >> 16;
}
__device__ __forceinline__ float bf2f(unsigned short u) {
    unsigned v = ((unsigned)u) << 16;
    return __builtin_bit_cast(float, v);
}
__device__ __forceinline__ int swz(int d) { return ((d >> 2) ^ d) & 7; }

// Kernel 1: per (batch, k-chunk) partial Gram via bf16 MFMA.
// 512 threads / 8 waves, 32x64 output slab per wave -> 32 AGPRs + ~80 VGPRs
// => 4 waves/SIMD (vs 2 in R3). Single-barrier ping-pong LDS: loads for t+1
// issue before the MFMA section, so the barrier's vmcnt drain is covered.
template<int P>
__global__ __launch_bounds__(512, 4) void gram_stats(
    const float* __restrict__ x, unsigned short* __restrict__ Spart,
    float* __restrict__ CSpart, float* __restrict__ KDpart)
{
    __shared__ short XT[2][DD * BK];   // ping-pong, 2 x 16 KB
    constexpr int rowsPerBlk = NPTS / P;
    constexpr int T = rowsPerBlk / BK;

    const int blk = blockIdx.x;
    const int b   = blk & 31;
    const int kc  = blk >> 5;
    const int k0g = kc * rowsPerBlk;
    const float* xb = x + (size_t)b * NPTS * DD;

    const int tid    = threadIdx.x;
    const int lane   = tid & 63;
    const int wave   = tid >> 6;      // 0..7
    const int dg     = tid & 31;      // d-group: owns d = 4*dg+i
    const int rowgrp = tid >> 5;      // 0..15: owns k-rows rowgrp*4 + r
    const int chunk  = rowgrp >> 1;   // k>>3 of owned rows
    const int wr32   = (wave & 3) * 32;
    const int wc64   = (wave >> 2) * 64;

    f32x16 acc0 = {}; f32x16 acc1 = {};
    float csum[4] = {0.f, 0.f, 0.f, 0.f};
    float kdot[4] = {0.f, 0.f, 0.f, 0.f};
    float4 R0, R1, R2, R3;

    auto issueLoads = [&](int kt) {
        const float4* s = (const float4*)(xb + (size_t)(k0g + kt + rowgrp * 4) * DD) + dg;
        R0 = s[0]; R1 = s[32]; R2 = s[64]; R3 = s[96];
    };
    auto convertStore = [&](int buf) {
        float x00 = __shfl(R0.x, lane & 32);
        float x01 = __shfl(R1.x, lane & 32);
        float x02 = __shfl(R2.x, lane & 32);
        float x03 = __shfl(R3.x, lane & 32);
        float e0[4] = {R0.x, R0.y, R0.z, R0.w};
        float e1[4] = {R1.x, R1.y, R1.z, R1.w};
        float e2[4] = {R2.x, R2.y, R2.z, R2.w};
        float e3[4] = {R3.x, R3.y, R3.z, R3.w};
        short* Xb = XT[buf];
        #pragma unroll
        for (int i = 0; i < 4; ++i) {
            csum[i] += e0[i] + e1[i] + e2[i] + e3[i];
            kdot[i] += x00 * e0[i] + x01 * e1[i] + x02 * e2[i] + x03 * e3[i];
            const int d = 4 * dg + i;
            unsigned u0 = f2bf_u(e0[i]) | (f2bf_u(e1[i]) << 16);
            unsigned u1 = f2bf_u(e2[i]) | (f2bf_u(e3[i]) << 16);
            const int addr = d * BK + ((chunk ^ swz(d)) * 8) + (rowgrp & 1) * 4;
            uint2 v; v.x = u0; v.y = u1;
            *(uint2*)(Xb + addr) = v;
        }
    };

    issueLoads(0);
    convertStore(0);
    __syncthreads();

    for (int t = 0; t < T; ++t) {
        if (t + 1 < T) issueLoads((t + 1) * BK);   // in flight across MFMA section
        const short* Xb = XT[t & 1];
        #pragma unroll
        for (int ks = 0; ks < BK / 16; ++ks) {
            const int cb = ks * 2 + (lane >> 5);
            const int m = lane & 31;
            const int ad = wr32 + m, b0d = wc64 + m, b1d = wc64 + 32 + m;
            bf16x8 a  = *(const bf16x8*)(Xb + ad  * BK + ((cb ^ swz(ad))  * 8));
            bf16x8 b0 = *(const bf16x8*)(Xb + b0d * BK + ((cb ^ swz(b0d)) * 8));
            bf16x8 b1 = *(const bf16x8*)(Xb + b1d * BK + ((cb ^ swz(b1d)) * 8));
            acc0 = __builtin_amdgcn_mfma_f32_32x32x16_bf16(a, b0, acc0, 0, 0, 0);
            acc1 = __builtin_amdgcn_mfma_f32_32x32x16_bf16(a, b1, acc1, 0, 0, 0);
        }
        if (t + 1 < T) convertStore((t + 1) & 1);
        __syncthreads();   // one barrier/iter: protects both ping-pong halves
    }

    // write partial Gram bf16 (C/D: col=lane&31, row=(r&3)+8*(r>>2)+4*(lane>>5))
    unsigned short* Sp = Spart + ((size_t)b * P + kc) * (DD * DD);
    const int colLane = lane & 31;
    const int rowHw = 4 * (lane >> 5);
    #pragma unroll
    for (int r = 0; r < 16; ++r) {
        const int row = wr32 + (r & 3) + 8 * (r >> 2) + rowHw;
        Sp[row * DD + wc64 + colLane]      = (unsigned short)f2bf_u(acc0[r]);
        Sp[row * DD + wc64 + 32 + colLane] = (unsigned short)f2bf_u(acc1[r]);
    }

    // block-reduce colsum / keydot (16 partial holders per (dg,i))
    __syncthreads();
    float* red = (float*)XT;
    #pragma unroll
    for (int i = 0; i < 4; ++i) {
        red[tid] = csum[i];
        __syncthreads();
        if (tid < 32) {
            float s = 0.f;
            #pragma unroll
            for (int g = 0; g < 16; ++g) s += red[g * 32 + tid];
            CSpart[((size_t)b * P + kc) * DD + 4 * tid + i] = s;
        }
        __syncthreads();
        red[tid] = kdot[i];
        __syncthreads();
        if (tid < 32) {
            float s = 0.f;
            #pragma unroll
            for (int g = 0; g < 16; ++g) s += red[g * 32 + tid];
            KDpart[((size_t)b * P + kc) * DD + 4 * tid + i] = s;
        }
        __syncthreads();
    }
}

// Kernel 2: one block per batch — reduce fp32 colsums/key-dots, compute keys,
// rank rows by fp32 key (index tie-break), store cs + ranks.
template<int P>
__global__ __launch_bounds__(128) void keys_ranks(
    const float* __restrict__ CSpart, const float* __restrict__ KDpart,
    float* __restrict__ csOut, int* __restrict__ rankOut)
{
    __shared__ float csh[DD];
    __shared__ float key[DD];
    const int b = blockIdx.x;
    const int tid = threadIdx.x;   // 128
    float s = 0.f, kd = 0.f;
    #pragma unroll
    for (int p = 0; p < P; ++p) {
        s  += CSpart[((size_t)b * P + p) * DD + tid];
        kd += KDpart[((size_t)b * P + p) * DD + tid];
    }
    csh[tid] = s;
    __syncthreads();
    const float k = (kd - s * csh[0] * (1.f / NPTS)) * (1.f / (NPTS - 1))
                  + ((tid == 0) ? LAM : 0.f);
    key[tid] = k;
    __syncthreads();
    int r = 0;
    #pragma unroll 8
    for (int j = 0; j < DD; ++j) {
        const float kj = key[j];
        r += (kj < k) || (kj == k && j < tid);
    }
    csOut[b * DD + tid] = s;
    rankOut[b * DD + tid] = r;
}

// Kernel 3: block (b, seg of 8 rows) — reduce bf16 partial Grams, fixup
// mean/ridge, scatter rows to ranked position in d_out.
template<int P>
__global__ __launch_bounds__(256) void reduce_scatter(
    const unsigned short* __restrict__ Spart, const float* __restrict__ csOut,
    const int* __restrict__ rankOut, float* __restrict__ out)
{
    __shared__ float csh[DD];
    __shared__ int rk[8];
    const int b = blockIdx.x;
    const int seg = blockIdx.y;
    const int tid = threadIdx.x;
    if (tid < DD) csh[tid] = csOut[b * DD + tid];
    if (tid < 8)  rk[tid] = rankOut[b * DD + seg * 8 + tid];

    const int base = seg * (8 * DD) + tid * 4;
    float a0 = 0.f, a1 = 0.f, a2 = 0.f, a3 = 0.f;
    #pragma unroll
    for (int p = 0; p < P; ++p) {
        uint2 v = *(const uint2*)(Spart + ((size_t)b * P + p) * (DD * DD) + base);
        a0 += bf2f((unsigned short)(v.x & 0xFFFFu));
        a1 += bf2f((unsigned short)(v.x >> 16));
        a2 += bf2f((unsigned short)(v.y & 0xFFFFu));
        a3 += bf2f((unsigned short)(v.y >> 16));
    }
    __syncthreads();
    const int row = seg * 8 + (tid >> 5);
    const int j0  = (tid & 31) * 4;
    const float ci = csh[row];
    const float invN = 1.f / NPTS, invNm1 = 1.f / (NPTS - 1);
    float4 v;
    v.x = (a0 - ci * csh[j0 + 0] * invN) * invNm1 + ((row == j0 + 0) ? LAM : 0.f);
    v.y = (a1 - ci * csh[j0 + 1] * invN) * invNm1 + ((row == j0 + 1) ? LAM : 0.f);
    v.z = (a2 - ci * csh[j0 + 2] * invN) * invNm1 + ((row == j0 + 2) ? LAM : 0.f);
    v.w = (a3 - ci * csh[j0 + 3] * invN) * invNm1 + ((row == j0 + 3) ? LAM : 0.f);
    float* o = out + (size_t)b * DD * DD + (size_t)rk[tid >> 5] * DD + j0;
    *(float4*)o = v;
}

template<int P>
static void launch_all(const float* x, float* out, void* d_ws, hipStream_t stream)
{
    size_t nS = (size_t)BBATCH * P * DD * DD;           // shorts
    unsigned short* Spart = (unsigned short*)d_ws;
    float* CSpart = (float*)(Spart + nS);
    float* KDpart = CSpart + (size_t)BBATCH * P * DD;
    float* csOut  = KDpart + (size_t)BBATCH * P * DD;
    int*   rankOut = (int*)(csOut + (size_t)BBATCH * DD);

    gram_stats<P><<<dim3(32 * P), dim3(512), 0, stream>>>(x, Spart, CSpart, KDpart);
    keys_ranks<P><<<dim3(BBATCH), dim3(128), 0, stream>>>(CSpart, KDpart, csOut, rankOut);
    reduce_scatter<P><<<dim3(BBATCH, 16), dim3(256), 0, stream>>>(Spart, csOut, rankOut, out);
}

extern "C" void kernel_launch(void* const* d_in, const int* in_sizes, int n_in,
                              void* d_out, int out_size, void* d_ws, size_t ws_size,
                              hipStream_t stream)
{
    const float* x = (const float*)d_in[0];
    float* out = (float*)d_out;

    auto need = [](int P) {
        return (size_t)BBATCH * P * DD * DD * sizeof(unsigned short)
             + (size_t)BBATCH * P * 2 * DD * sizeof(float)
             + (size_t)BBATCH * DD * (sizeof(float) + sizeof(int));
    };
    if (need(16) <= ws_size)      launch_all<16>(x, out, d_ws, stream);
    else                          launch_all<8>(x, out, d_ws, stream);
}